// Round 3
// baseline (831.910 us; speedup 1.0000x reference)
//
#include <hip/hip_runtime.h>

#define N2 65536
#define FW 768

// ---------------- workspace layout (float offsets) ----------------
#define WS_CHARGE 0
#define WS_ILLUM  (N2)
#define WS_SENS   (2*N2)
#define WS_FEAT2  (3*N2)              // 32 x 256 x 256, CHW
#define WS_W1T    (35*N2)             // [k*32+co]           288
#define WS_W2T    (WS_W1T + 288)      // [(ci*9+k)*32+co]    9216
#define WS_W3T    (WS_W2T + 9216)     // [(ci*9+k)*12+co]    3456
#define WS_SUMS   (WS_W3T + 3456)     // 9 charge sums
#define WS_MEANB  (WS_SUMS + 9)
#define WS_MEDIAN (WS_SUMS + 10)

__device__ __forceinline__ void block_sum_atomic(float v, float* dst){
  #pragma unroll
  for (int o = 32; o > 0; o >>= 1) v += __shfl_down(v, o, 64);
  __shared__ float red[8];
  int lane = threadIdx.x & 63, wid = threadIdx.x >> 6;
  int nw = (int)(blockDim.x >> 6);
  if (lane == 0) red[wid] = v;
  __syncthreads();
  if (threadIdx.x == 0){
    float s = red[0];
    for (int w = 1; w < nw; w++) s += red[w];
    atomicAdd(dst, s);
  }
}

// inclusive block scan (blockDim multiple of 64, <=1024)
__device__ __forceinline__ unsigned block_scan_u32(unsigned v, unsigned* wsum){
  __syncthreads();
  int lane = threadIdx.x & 63, wid = threadIdx.x >> 6, nw = (int)(blockDim.x >> 6);
  unsigned x = v;
  #pragma unroll
  for (int o = 1; o < 64; o <<= 1){ unsigned y = __shfl_up(x, o, 64); if (lane >= o) x += y; }
  if (lane == 63) wsum[wid] = x;
  __syncthreads();
  if (wid == 0){
    unsigned w = (lane < nw) ? wsum[lane] : 0u;
    #pragma unroll
    for (int o = 1; o < 16; o <<= 1){ unsigned y = __shfl_up(w, o, 64); if (lane >= o) w += y; }
    if (lane < nw) wsum[lane] = w;
  }
  __syncthreads();
  unsigned base = (wid > 0) ? wsum[wid - 1] : 0u;
  return base + x;
}

// ---- single-kernel: weight transpose + bias mean + exact median (3-level radix) ----
__global__ __launch_bounds__(1024) void k_median(const float* __restrict__ bias,
    const float* __restrict__ w1, const float* __restrict__ w2,
    const float* __restrict__ w3, float* __restrict__ ws){
  int t = threadIdx.x;
  for (int idx = t; idx < 288; idx += 1024){
    int co = idx / 9, k = idx - co*9;
    ws[WS_W1T + k*32 + co] = w1[idx];
  }
  for (int idx = t; idx < 9216; idx += 1024){
    int co = idx / 288, r = idx - co*288, ci = r / 9, k = r - ci*9;
    ws[WS_W2T + (ci*9 + k)*32 + co] = w2[idx];
  }
  for (int idx = t; idx < 3456; idx += 1024){
    int co = idx / 288, r = idx - co*288, ci = r / 9, k = r - ci*9;
    ws[WS_W3T + (ci*9 + k)*12 + co] = w3[idx];
  }

  __shared__ unsigned h[4096];
  __shared__ unsigned wssc[16];
  __shared__ unsigned selp[2], selk[2];
  __shared__ float meds[2];
  __shared__ float fred[16];

  for (int i = t; i < 4096; i += 1024) h[i] = 0u;
  __syncthreads();
  float sum = 0.f;
  for (int i = t; i < N2; i += 1024){
    float v = bias[i]; sum += v;
    unsigned u = __float_as_uint(v);
    unsigned key = (u & 0x80000000u) ? ~u : (u ^ 0x80000000u);
    atomicAdd(&h[key >> 20], 1u);
  }
  #pragma unroll
  for (int o = 32; o > 0; o >>= 1) sum += __shfl_down(sum, o, 64);
  if ((t & 63) == 0) fred[t >> 6] = sum;

  // level 1: 4096 bins, chunk-of-4 scan
  unsigned c4 = h[4*t] + h[4*t+1] + h[4*t+2] + h[4*t+3];
  unsigned cum = block_scan_u32(c4, wssc);
  {
    unsigned before = cum - c4;
    for (int s = 0; s < 2; s++){
      unsigned rank = 32767u + (unsigned)s;
      if (before <= rank && rank < cum){
        unsigned kk = rank - before, acc = 0; int b = 0;
        for (; b < 3; b++){ unsigned hh = h[4*t + b]; if (acc + hh > kk) break; acc += hh; }
        selp[s] = (unsigned)(4*t + b);
        selk[s] = kk - acc;
      }
    }
  }
  __syncthreads();

  // levels 2 and 3: 1024-bin gated hists (two targets each)
  for (int lvl = 0; lvl < 2; lvl++){
    unsigned shift = (lvl == 0) ? 10u : 0u;
    unsigned p0 = selp[0], p1 = selp[1];
    __syncthreads();
    for (int i = t; i < 2048; i += 1024) h[i] = 0u;
    __syncthreads();
    for (int i = t; i < N2; i += 1024){
      unsigned u = __float_as_uint(bias[i]);
      unsigned key = (u & 0x80000000u) ? ~u : (u ^ 0x80000000u);
      unsigned top = key >> (shift + 10u);
      unsigned bin = (key >> shift) & 1023u;
      if (top == p0) atomicAdd(&h[bin], 1u);
      if (top == p1) atomicAdd(&h[1024u + bin], 1u);
    }
    __syncthreads();
    for (int s = 0; s < 2; s++){
      unsigned cc = h[s*1024 + t];
      unsigned rank = selk[s];
      unsigned cm = block_scan_u32(cc, wssc);
      unsigned before = cm - cc;
      if (before <= rank && rank < cm){
        selp[s] = (selp[s] << 10) | (unsigned)t;
        selk[s] = rank - before;
        if (lvl == 1){
          unsigned key = selp[s];
          unsigned u = (key & 0x80000000u) ? (key ^ 0x80000000u) : ~key;
          meds[s] = __uint_as_float(u);
        }
      }
      __syncthreads();
    }
  }
  if (t == 0){
    float bs = 0.f;
    #pragma unroll
    for (int i = 0; i < 16; i++) bs += fred[i];
    ws[WS_MEANB]  = bs * (1.f / (float)N2);
    ws[WS_MEDIAN] = 0.5f * (meds[0] + meds[1]);
  }
  if (t < 9) ws[WS_SUMS + t] = 0.f;
}

// ---- init: downsample illum/sens, charge init, ramp[0], charge sum ----
__global__ __launch_bounds__(256) void k_init(const float* __restrict__ bias,
    const float* __restrict__ illum, const float* __restrict__ sens,
    float* __restrict__ ws, float* __restrict__ out){
  int pix = blockIdx.x * 256 + threadIdx.x;
  int i = pix >> 8, j = pix & 255;
  float si = 0.f, ss = 0.f;
  #pragma unroll
  for (int p = 0; p < 3; p++)
    #pragma unroll
    for (int q = 0; q < 3; q++){
      float se = sens[(3*i+p)*FW + 3*j+q];
      float il = illum[(3*i+p)*FW + 3*j+q];
      si = fmaf(se, il * 0.125f, si);
      ss += se;
    }
  ws[WS_ILLUM + pix] = si;
  ws[WS_SENS  + pix] = ss * (1.f/9.f);
  float c = bias[pix] - ws[WS_MEANB];
  ws[WS_CHARGE + pix] = c;
  out[pix] = c + ws[WS_MEDIAN];
  block_sum_atomic(c, ws + WS_SUMS + 0);
}

// ---- convA: conv1(1->32)+relu + conv2(32->32)+relu -> feat2 (global) ----
// 256 blocks x 512 threads. conv2: 8 waves x 4co, lane = 4px; weights via
// wave-uniform (readfirstlane) scalar loads -> SMEM pipe.
__global__ __launch_bounds__(512) void k_convA(float* __restrict__ ws,
    const float* __restrict__ w1t, const float* __restrict__ w2t, int step){
  __shared__ float chg[400];         // 20x20 charge tile (halo 2)
  __shared__ float f1[32*360];       // [ci][18 rows][20 cols]
  const float* charge = ws + WS_CHARGE;
  const float mean = ws[WS_SUMS + step] * (1.f / (float)N2);
  const int gi0 = (blockIdx.x >> 4) << 4, gj0 = (blockIdx.x & 15) << 4;
  const int tid = threadIdx.x;

  if (tid < 400){
    int r = tid / 20, c = tid - r*20;
    int gi = gi0 + r - 2, gj = gj0 + c - 2;
    float v = 0.f;
    if ((unsigned)gi < 256u && (unsigned)gj < 256u) v = charge[(gi<<8) + gj] - mean;
    chg[tid] = v;
  }
  __syncthreads();

  if (tid < 324){
    int r = tid / 18, c = tid - r*18;
    int gi = gi0 + r - 1, gj = gj0 + c - 1;
    float acc[32];
    #pragma unroll
    for (int co = 0; co < 32; co++) acc[co] = 0.f;
    if ((unsigned)gi < 256u && (unsigned)gj < 256u){
      float x[9];
      #pragma unroll
      for (int dy = 0; dy < 3; dy++)
        #pragma unroll
        for (int dx = 0; dx < 3; dx++) x[dy*3+dx] = chg[(r+dy)*20 + c+dx];
      #pragma unroll
      for (int k = 0; k < 9; k++){
        float xv = x[k];
        const float4* wr = (const float4*)(w1t + k*32);
        #pragma unroll
        for (int g = 0; g < 8; g++){
          float4 w4 = wr[g];
          acc[g*4+0] = fmaf(w4.x, xv, acc[g*4+0]);
          acc[g*4+1] = fmaf(w4.y, xv, acc[g*4+1]);
          acc[g*4+2] = fmaf(w4.z, xv, acc[g*4+2]);
          acc[g*4+3] = fmaf(w4.w, xv, acc[g*4+3]);
        }
      }
      #pragma unroll
      for (int co = 0; co < 32; co++) acc[co] = fmaxf(acc[co], 0.f);
    }
    #pragma unroll
    for (int co = 0; co < 32; co++) f1[co*360 + r*20 + c] = acc[co];
  }
  __syncthreads();

  const int lane = tid & 63;
  const int co4 = __builtin_amdgcn_readfirstlane((tid >> 6) << 2);
  const int ti = lane >> 2, tjc = (lane & 3) << 2;
  float acc[4][4];
  #pragma unroll
  for (int p = 0; p < 4; p++)
    #pragma unroll
    for (int cc = 0; cc < 4; cc++) acc[p][cc] = 0.f;

  const float* wb = w2t + co4;
  for (int ci = 0; ci < 32; ci++){
    float xr[3][6];
    #pragma unroll
    for (int dy = 0; dy < 3; dy++){
      const float* rp = f1 + ci*360 + (ti+dy)*20 + tjc;
      float4 a = *(const float4*)rp;
      float2 b = *(const float2*)(rp + 4);
      xr[dy][0] = a.x; xr[dy][1] = a.y; xr[dy][2] = a.z; xr[dy][3] = a.w;
      xr[dy][4] = b.x; xr[dy][5] = b.y;
    }
    const float* wci = wb + ci*288;
    #pragma unroll
    for (int k = 0; k < 9; k++){
      const int dy = k / 3, dx = k - dy*3;
      float4 w4 = *(const float4*)(wci + k*32);
      #pragma unroll
      for (int p = 0; p < 4; p++){
        float xv = xr[dy][p + dx];
        acc[p][0] = fmaf(w4.x, xv, acc[p][0]);
        acc[p][1] = fmaf(w4.y, xv, acc[p][1]);
        acc[p][2] = fmaf(w4.z, xv, acc[p][2]);
        acc[p][3] = fmaf(w4.w, xv, acc[p][3]);
      }
    }
  }
  float* f2 = ws + WS_FEAT2;
  const int prow = ((gi0 + ti) << 8) + gj0 + tjc;
  #pragma unroll
  for (int cc = 0; cc < 4; cc++){
    float4 v;
    v.x = fmaxf(acc[0][cc], 0.f);
    v.y = fmaxf(acc[1][cc], 0.f);
    v.z = fmaxf(acc[2][cc], 0.f);
    v.w = fmaxf(acc[3][cc], 0.f);
    *(float4*)(f2 + (co4 + cc)*N2 + prow) = v;
  }
}

// ---- convB: conv3(32->12) on 18x18 halo tile + distortion/overlap -> S (LDS)
//      + fused apply/charge-update/outputs. 256 blocks x 512 threads. ----
__global__ __launch_bounds__(512) void k_convB(float* __restrict__ ws,
    const float* __restrict__ w3t, const float* __restrict__ illum,
    float* __restrict__ out, int step){
  __shared__ float tile[32*400];     // [ci][20x20] f2 tile (halo 2)
  __shared__ float coef[324*12];     // per-px conv3 coeffs (reduced)
  __shared__ float S[9*324];         // S planes on 18x18
  const float* f2 = ws + WS_FEAT2;
  const int gi0 = (blockIdx.x >> 4) << 4, gj0 = (blockIdx.x & 15) << 4;
  const int tid = threadIdx.x;

  if (tid < 400){
    int r = tid / 20, c = tid - r*20;
    int gi = gi0 + r - 2, gj = gj0 + c - 2;
    bool in = (unsigned)gi < 256u && (unsigned)gj < 256u;
    int gidx = (gi << 8) + gj;
    for (int ci = 0; ci < 32; ci++){
      float v = in ? f2[ci*N2 + gidx] : 0.f;
      tile[ci*400 + tid] = v;
    }
  }
  for (int i = tid; i < 324*12; i += 512) coef[i] = 0.f;
  __syncthreads();

  // conv3 split into (px, ci-quarter) items for wave balance
  for (int item = tid; item < 1296; item += 512){
    int q = item / 324, px = item - q*324;
    int a = px / 18, b = px - a*18;
    int gi = gi0 + a - 1, gj = gj0 + b - 1;
    if ((unsigned)gi < 256u && (unsigned)gj < 256u){
      float acc[12];
      #pragma unroll
      for (int co = 0; co < 12; co++) acc[co] = 0.f;
      int ci0 = q * 8;
      for (int ci = ci0; ci < ci0 + 8; ci++){
        float x[9];
        #pragma unroll
        for (int dy = 0; dy < 3; dy++)
          #pragma unroll
          for (int dx = 0; dx < 3; dx++) x[dy*3+dx] = tile[ci*400 + (a+dy)*20 + (b+dx)];
        #pragma unroll
        for (int k = 0; k < 9; k++){
          const float4* wr = (const float4*)(w3t + (ci*9 + k)*12);
          float4 A = wr[0], B = wr[1], C = wr[2];
          float xv = x[k];
          acc[0] = fmaf(A.x, xv, acc[0]);   acc[1] = fmaf(A.y, xv, acc[1]);
          acc[2] = fmaf(A.z, xv, acc[2]);   acc[3] = fmaf(A.w, xv, acc[3]);
          acc[4] = fmaf(B.x, xv, acc[4]);   acc[5] = fmaf(B.y, xv, acc[5]);
          acc[6] = fmaf(B.z, xv, acc[6]);   acc[7] = fmaf(B.w, xv, acc[7]);
          acc[8] = fmaf(C.x, xv, acc[8]);   acc[9] = fmaf(C.y, xv, acc[9]);
          acc[10] = fmaf(C.z, xv, acc[10]); acc[11] = fmaf(C.w, xv, acc[11]);
        }
      }
      #pragma unroll
      for (int co = 0; co < 12; co++) atomicAdd(&coef[px*12 + co], acc[co]);
    }
  }
  __syncthreads();

  if (tid < 324){
    int a = tid / 18, b = tid - a*18;
    int gi = gi0 + a - 1, gj = gj0 + b - 1;
    float Sv[9];
    #pragma unroll
    for (int d = 0; d < 9; d++) Sv[d] = 0.f;
    if ((unsigned)gi < 256u && (unsigned)gj < 256u){
      float cf[12];
      #pragma unroll
      for (int co = 0; co < 12; co++) cf[co] = coef[tid*12 + co];
      const float third = 1.f/3.f, sixth = 1.f/6.f;
      #pragma unroll
      for (int p = 0; p < 3; p++){
        float kx = (p - 1) * third;
        #pragma unroll
        for (int q = 0; q < 3; q++){
          float ky = (q - 1) * third;
          float cx = kx + cf[0] + cf[1]*ky + cf[2]*kx + cf[3]*ky*ky + cf[4]*kx*ky + cf[5]*kx*kx;
          float cy = ky + cf[6] + cf[7]*ky + cf[8]*kx + cf[9]*ky*ky + cf[10]*kx*ky + cf[11]*kx*kx;
          float Ipq = illum[(3*gi+p)*FW + 3*gj+q] * 0.125f;
          float ox[3], oy[3];
          #pragma unroll
          for (int d = 0; d < 3; d++){
            float xx = cx + (float)(d - 1);
            ox[d] = fmaxf(0.f, fminf(xx + sixth, 0.5f) - fmaxf(xx - sixth, -0.5f));
            float yy = cy + (float)(d - 1);
            oy[d] = fmaxf(0.f, fminf(yy + sixth, 0.5f) - fmaxf(yy - sixth, -0.5f));
          }
          #pragma unroll
          for (int d = 0; d < 3; d++){
            float aa = Ipq * ox[d];
            #pragma unroll
            for (int e = 0; e < 3; e++) Sv[d*3+e] = fmaf(aa, oy[e], Sv[d*3+e]);
          }
        }
      }
    }
    #pragma unroll
    for (int d = 0; d < 9; d++) S[d*324 + tid] = Sv[d];
  }
  __syncthreads();

  float chv = 0.f;
  if (tid < 256){
    int ti = tid >> 4, tj = tid & 15;
    float s = 0.f;
    #pragma unroll
    for (int d = 0; d < 3; d++)
      #pragma unroll
      for (int e = 0; e < 3; e++) s += S[(d*3+e)*324 + (ti+d)*18 + tj+e];
    int pix = ((gi0 + ti) << 8) + gj0 + tj;
    float nc = ws[WS_SENS + pix] * (9.f * s);
    float ch = ws[WS_CHARGE + pix] + nc;
    ws[WS_CHARGE + pix] = ch;
    out[(step + 1)*N2 + pix] = ch + ws[WS_MEDIAN];
    out[(9 + step)*N2 + pix] = ws[WS_ILLUM + pix] - nc;
    chv = ch;
  }
  block_sum_atomic(chv, ws + WS_SUMS + step + 1);
}

extern "C" void kernel_launch(void* const* d_in, const int* in_sizes, int n_in,
                              void* d_out, int out_size, void* d_ws, size_t ws_size,
                              hipStream_t stream) {
  (void)in_sizes; (void)n_in; (void)out_size; (void)ws_size;
  const float* bias  = (const float*)d_in[0];
  const float* illum = (const float*)d_in[1];
  const float* sens  = (const float*)d_in[2];
  const float* w1    = (const float*)d_in[3];
  const float* w2    = (const float*)d_in[4];
  const float* w3    = (const float*)d_in[5];
  float* out = (float*)d_out;
  float* ws  = (float*)d_ws;

  k_median<<<1, 1024, 0, stream>>>(bias, w1, w2, w3, ws);
  k_init  <<<256, 256, 0, stream>>>(bias, illum, sens, ws, out);
  for (int t = 0; t < 8; t++){
    k_convA<<<256, 512, 0, stream>>>(ws, ws + WS_W1T, ws + WS_W2T, t);
    k_convB<<<256, 512, 0, stream>>>(ws, ws + WS_W3T, illum, out, t);
  }
}

// Round 6
// 648.568 us; speedup vs baseline: 1.2827x; 1.2827x over previous
//
#include <hip/hip_runtime.h>

#define N2 65536
#define FW 768

// ---------------- workspace layout (float offsets) ----------------
#define WS_CHARGE 0
#define WS_ILLUM  (N2)
#define WS_SENS   (2*N2)
#define WS_FEAT2  (3*N2)              // 32 x 256 x 256, CHW
#define WS_W1T    (35*N2)             // [k*32+co]           288
#define WS_W2T    (WS_W1T + 288)      // [(ci*9+k)*32+co]    9216
#define WS_W3T    (WS_W2T + 9216)     // [(ci*9+k)*12+co]    3456
#define WS_SUMS   (WS_W3T + 3456)     // 9 charge sums
#define WS_BSUM   (WS_SUMS + 9)
#define WS_MEANB  (WS_SUMS + 10)
#define WS_MEDIAN (WS_SUMS + 11)
#define WS_SEL    (WS_SUMS + 12)      // 4 u32: selp0, selp1, selk0, selk1
#define WS_H1     (WS_SUMS + 16)      // 4096 u32
#define WS_H2     (WS_H1 + 4096)      // 2048 u32
#define WS_H3     (WS_H2 + 2048)      // 2048 u32
#define NCLEAR    (16 + 4096 + 2048 + 2048)

__device__ __forceinline__ void block_sum_atomic(float v, float* dst){
  #pragma unroll
  for (int o = 32; o > 0; o >>= 1) v += __shfl_down(v, o, 64);
  __shared__ float red[16];
  int lane = threadIdx.x & 63, wid = threadIdx.x >> 6;
  int nw = (int)(blockDim.x >> 6);
  if (lane == 0) red[wid] = v;
  __syncthreads();
  if (threadIdx.x == 0){
    float s = red[0];
    for (int w = 1; w < nw; w++) s += red[w];
    atomicAdd(dst, s);
  }
}

// inclusive block scan (blockDim multiple of 64, <=1024)
__device__ __forceinline__ unsigned block_scan_u32(unsigned v, unsigned* wsum){
  __syncthreads();
  int lane = threadIdx.x & 63, wid = threadIdx.x >> 6, nw = (int)(blockDim.x >> 6);
  unsigned x = v;
  #pragma unroll
  for (int o = 1; o < 64; o <<= 1){ unsigned y = __shfl_up(x, o, 64); if (lane >= o) x += y; }
  if (lane == 63) wsum[wid] = x;
  __syncthreads();
  if (wid == 0){
    unsigned w = (lane < nw) ? wsum[lane] : 0u;
    #pragma unroll
    for (int o = 1; o < 16; o <<= 1){ unsigned y = __shfl_up(w, o, 64); if (lane >= o) w += y; }
    if (lane < nw) wsum[lane] = w;
  }
  __syncthreads();
  unsigned base = (wid > 0) ? wsum[wid - 1] : 0u;
  return base + x;
}

__device__ __forceinline__ unsigned key_flip(unsigned u){
  return (u & 0x80000000u) ? ~u : (u ^ 0x80000000u);
}

// ---- prep: zero hist/accumulator region + weight transpose (8 blocks) ----
__global__ __launch_bounds__(256) void k_prep(const float* __restrict__ w1,
    const float* __restrict__ w2, const float* __restrict__ w3,
    float* __restrict__ ws){
  int t = blockIdx.x * 256 + threadIdx.x;   // 2048 threads total
  unsigned* z = (unsigned*)(ws + WS_SUMS);
  for (int i = t; i < NCLEAR; i += 2048) z[i] = 0u;
  for (int idx = t; idx < 288; idx += 2048){
    int co = idx / 9, k = idx - co*9;
    ws[WS_W1T + k*32 + co] = w1[idx];
  }
  for (int idx = t; idx < 9216; idx += 2048){
    int co = idx / 288, r = idx - co*288, ci = r / 9, k = r - ci*9;
    ws[WS_W2T + (ci*9 + k)*32 + co] = w2[idx];
  }
  for (int idx = t; idx < 3456; idx += 2048){
    int co = idx / 288, r = idx - co*288, ci = r / 9, k = r - ci*9;
    ws[WS_W3T + (ci*9 + k)*12 + co] = w3[idx];
  }
}

// ---- level-1 histogram (4096 bins, key>>20) + bias sum ----
__global__ __launch_bounds__(256) void k_h1(const float* __restrict__ bias,
                                            float* __restrict__ ws){
  unsigned* H1 = (unsigned*)(ws + WS_H1);
  float s = 0.f;
  for (int i = blockIdx.x * 256 + threadIdx.x; i < N2; i += 64*256){
    float v = bias[i]; s += v;
    atomicAdd(&H1[key_flip(__float_as_uint(v)) >> 20], 1u);
  }
  block_sum_atomic(s, ws + WS_BSUM);
}

// ---- scan level-1: ranks 32767/32768 -> sel; finalize mean ----
__global__ __launch_bounds__(1024) void k_s1(float* __restrict__ ws){
  const unsigned* H1 = (const unsigned*)(ws + WS_H1);
  unsigned* sel = (unsigned*)(ws + WS_SEL);
  __shared__ unsigned wssc[16];
  int t = threadIdx.x;
  uint4 h4 = ((const uint4*)H1)[t];
  unsigned c4 = h4.x + h4.y + h4.z + h4.w;
  unsigned cum = block_scan_u32(c4, wssc);
  unsigned before = cum - c4;
  unsigned hh[4] = {h4.x, h4.y, h4.z, h4.w};
  for (int s = 0; s < 2; s++){
    unsigned rank = 32767u + (unsigned)s;
    if (before <= rank && rank < cum){
      unsigned kk = rank - before, acc = 0; unsigned b = 0;
      for (; b < 3; b++){ if (acc + hh[b] > kk) break; acc += hh[b]; }
      sel[s]     = 4u*(unsigned)t + b;
      sel[2 + s] = kk - acc;
    }
  }
  if (t == 0) ws[WS_MEANB] = ws[WS_BSUM] * (1.f / (float)N2);
}

// ---- gated 1024-bin histogram (levels 2/3) ----
__global__ __launch_bounds__(256) void k_h23(const float* __restrict__ bias,
    float* __restrict__ ws, unsigned* __restrict__ H, int shift){
  const unsigned* sel = (const unsigned*)(ws + WS_SEL);
  unsigned p0 = sel[0], p1 = sel[1];
  for (int i = blockIdx.x * 256 + threadIdx.x; i < N2; i += 64*256){
    unsigned key = key_flip(__float_as_uint(bias[i]));
    unsigned top = key >> (shift + 10);
    unsigned bin = (key >> shift) & 1023u;
    if (top == p0) atomicAdd(&H[bin], 1u);
    if (top == p1) atomicAdd(&H[1024u + bin], 1u);
  }
}

// ---- scan levels 2/3 ----
__global__ __launch_bounds__(1024) void k_s23(float* __restrict__ ws,
    const unsigned* __restrict__ H, int final_lvl){
  unsigned* sel = (unsigned*)(ws + WS_SEL);
  __shared__ unsigned wssc[16];
  __shared__ float meds[2];
  int t = threadIdx.x;
  for (int s = 0; s < 2; s++){
    unsigned cc = H[s*1024 + t];
    unsigned rank = sel[2 + s];
    unsigned cum = block_scan_u32(cc, wssc);
    unsigned before = cum - cc;
    if (before <= rank && rank < cum){
      unsigned p = (sel[s] << 10) | (unsigned)t;
      sel[s]     = p;
      sel[2 + s] = rank - before;
      if (final_lvl){
        unsigned u = (p & 0x80000000u) ? (p ^ 0x80000000u) : ~p;
        meds[s] = __uint_as_float(u);
      }
    }
    __syncthreads();
  }
  if (final_lvl && t == 0) ws[WS_MEDIAN] = 0.5f * (meds[0] + meds[1]);
}

// ---- init: downsample illum/sens, charge init, ramp[0], charge sum ----
__global__ __launch_bounds__(256) void k_init(const float* __restrict__ bias,
    const float* __restrict__ illum, const float* __restrict__ sens,
    float* __restrict__ ws, float* __restrict__ out){
  int pix = blockIdx.x * 256 + threadIdx.x;
  int i = pix >> 8, j = pix & 255;
  float si = 0.f, ss = 0.f;
  #pragma unroll
  for (int p = 0; p < 3; p++)
    #pragma unroll
    for (int q = 0; q < 3; q++){
      float se = sens[(3*i+p)*FW + 3*j+q];
      float il = illum[(3*i+p)*FW + 3*j+q];
      si = fmaf(se, il * 0.125f, si);
      ss += se;
    }
  ws[WS_ILLUM + pix] = si;
  ws[WS_SENS  + pix] = ss * (1.f/9.f);
  float c = bias[pix] - ws[WS_MEANB];
  ws[WS_CHARGE + pix] = c;
  out[pix] = c + ws[WS_MEDIAN];
  block_sum_atomic(c, ws + WS_SUMS + 0);
}

// ---- convA: conv1(1->32)+relu + conv2(32->32)+relu -> feat2 (global) ----
__global__ __launch_bounds__(512) void k_convA(float* __restrict__ ws,
    const float* __restrict__ w1t, const float* __restrict__ w2t, int step){
  __shared__ float chg[400];         // 20x20 charge tile (halo 2)
  __shared__ float f1[32*360];       // [ci][18 rows][20 cols]
  const float* charge = ws + WS_CHARGE;
  const float mean = ws[WS_SUMS + step] * (1.f / (float)N2);
  const int gi0 = (blockIdx.x >> 4) << 4, gj0 = (blockIdx.x & 15) << 4;
  const int tid = threadIdx.x;

  if (tid < 400){
    int r = tid / 20, c = tid - r*20;
    int gi = gi0 + r - 2, gj = gj0 + c - 2;
    float v = 0.f;
    if ((unsigned)gi < 256u && (unsigned)gj < 256u) v = charge[(gi<<8) + gj] - mean;
    chg[tid] = v;
  }
  __syncthreads();

  if (tid < 324){
    int r = tid / 18, c = tid - r*18;
    int gi = gi0 + r - 1, gj = gj0 + c - 1;
    float acc[32];
    #pragma unroll
    for (int co = 0; co < 32; co++) acc[co] = 0.f;
    if ((unsigned)gi < 256u && (unsigned)gj < 256u){
      float x[9];
      #pragma unroll
      for (int dy = 0; dy < 3; dy++)
        #pragma unroll
        for (int dx = 0; dx < 3; dx++) x[dy*3+dx] = chg[(r+dy)*20 + c+dx];
      #pragma unroll
      for (int k = 0; k < 9; k++){
        float xv = x[k];
        const float4* wr = (const float4*)(w1t + k*32);
        #pragma unroll
        for (int g = 0; g < 8; g++){
          float4 w4 = wr[g];
          acc[g*4+0] = fmaf(w4.x, xv, acc[g*4+0]);
          acc[g*4+1] = fmaf(w4.y, xv, acc[g*4+1]);
          acc[g*4+2] = fmaf(w4.z, xv, acc[g*4+2]);
          acc[g*4+3] = fmaf(w4.w, xv, acc[g*4+3]);
        }
      }
      #pragma unroll
      for (int co = 0; co < 32; co++) acc[co] = fmaxf(acc[co], 0.f);
    }
    #pragma unroll
    for (int co = 0; co < 32; co++) f1[co*360 + r*20 + c] = acc[co];
  }
  __syncthreads();

  const int lane = tid & 63;
  const int co4 = __builtin_amdgcn_readfirstlane((tid >> 6) << 2);
  const int ti = lane >> 2, tjc = (lane & 3) << 2;
  float acc[4][4];
  #pragma unroll
  for (int p = 0; p < 4; p++)
    #pragma unroll
    for (int cc = 0; cc < 4; cc++) acc[p][cc] = 0.f;

  const float* wb = w2t + co4;
  for (int ci = 0; ci < 32; ci++){
    float xr[3][6];
    #pragma unroll
    for (int dy = 0; dy < 3; dy++){
      const float* rp = f1 + ci*360 + (ti+dy)*20 + tjc;
      float4 a = *(const float4*)rp;
      float2 b = *(const float2*)(rp + 4);
      xr[dy][0] = a.x; xr[dy][1] = a.y; xr[dy][2] = a.z; xr[dy][3] = a.w;
      xr[dy][4] = b.x; xr[dy][5] = b.y;
    }
    const float* wci = wb + ci*288;
    #pragma unroll
    for (int k = 0; k < 9; k++){
      const int dy = k / 3, dx = k - dy*3;
      float4 w4 = *(const float4*)(wci + k*32);
      #pragma unroll
      for (int p = 0; p < 4; p++){
        float xv = xr[dy][p + dx];
        acc[p][0] = fmaf(w4.x, xv, acc[p][0]);
        acc[p][1] = fmaf(w4.y, xv, acc[p][1]);
        acc[p][2] = fmaf(w4.z, xv, acc[p][2]);
        acc[p][3] = fmaf(w4.w, xv, acc[p][3]);
      }
    }
  }
  float* f2 = ws + WS_FEAT2;
  const int prow = ((gi0 + ti) << 8) + gj0 + tjc;
  #pragma unroll
  for (int cc = 0; cc < 4; cc++){
    float4 v;
    v.x = fmaxf(acc[0][cc], 0.f);
    v.y = fmaxf(acc[1][cc], 0.f);
    v.z = fmaxf(acc[2][cc], 0.f);
    v.w = fmaxf(acc[3][cc], 0.f);
    *(float4*)(f2 + (co4 + cc)*N2 + prow) = v;
  }
}

// ---- convB: conv3(32->12) on 18x18 halo (1 px/thread, registers only)
//      + distortion/overlap -> S (LDS) + fused apply. No atomics. ----
__global__ __launch_bounds__(512) void k_convB(float* __restrict__ ws,
    const float* __restrict__ w3t, const float* __restrict__ illum,
    float* __restrict__ out, int step){
  __shared__ float tile[32*400];     // [ci][20x20] f2 tile (halo 2)  51.2 KB
  __shared__ float S[9*324];         // S planes on 18x18             11.7 KB
  const float* f2 = ws + WS_FEAT2;
  const int gi0 = (blockIdx.x >> 4) << 4, gj0 = (blockIdx.x & 15) << 4;
  const int tid = threadIdx.x;

  for (int idx = tid; idx < 32*400; idx += 512){
    int ci = idx / 400, px = idx - ci*400, r = px / 20, c = px - r*20;
    int gi = gi0 + r - 2, gj = gj0 + c - 2;
    float v = 0.f;
    if ((unsigned)gi < 256u && (unsigned)gj < 256u) v = f2[ci*N2 + (gi<<8) + gj];
    tile[idx] = v;
  }
  __syncthreads();

  if (tid < 324){
    int a = tid / 18, b = tid - a*18;
    int gi = gi0 + a - 1, gj = gj0 + b - 1;
    float Sv[9];
    #pragma unroll
    for (int d = 0; d < 9; d++) Sv[d] = 0.f;
    if ((unsigned)gi < 256u && (unsigned)gj < 256u){
      float cf[12];
      #pragma unroll
      for (int co = 0; co < 12; co++) cf[co] = 0.f;
      for (int ci = 0; ci < 32; ci++){
        float x[9];
        #pragma unroll
        for (int dy = 0; dy < 3; dy++)
          #pragma unroll
          for (int dx = 0; dx < 3; dx++) x[dy*3+dx] = tile[ci*400 + (a+dy)*20 + (b+dx)];
        #pragma unroll
        for (int k = 0; k < 9; k++){
          const float4* wr = (const float4*)(w3t + (ci*9 + k)*12);
          float4 A = wr[0], B = wr[1], C = wr[2];
          float xv = x[k];
          cf[0] = fmaf(A.x, xv, cf[0]);   cf[1] = fmaf(A.y, xv, cf[1]);
          cf[2] = fmaf(A.z, xv, cf[2]);   cf[3] = fmaf(A.w, xv, cf[3]);
          cf[4] = fmaf(B.x, xv, cf[4]);   cf[5] = fmaf(B.y, xv, cf[5]);
          cf[6] = fmaf(B.z, xv, cf[6]);   cf[7] = fmaf(B.w, xv, cf[7]);
          cf[8] = fmaf(C.x, xv, cf[8]);   cf[9] = fmaf(C.y, xv, cf[9]);
          cf[10] = fmaf(C.z, xv, cf[10]); cf[11] = fmaf(C.w, xv, cf[11]);
        }
      }
      const float third = 1.f/3.f, sixth = 1.f/6.f;
      #pragma unroll
      for (int p = 0; p < 3; p++){
        float kx = (p - 1) * third;
        #pragma unroll
        for (int q = 0; q < 3; q++){
          float ky = (q - 1) * third;
          float cx = kx + cf[0] + cf[1]*ky + cf[2]*kx + cf[3]*ky*ky + cf[4]*kx*ky + cf[5]*kx*kx;
          float cy = ky + cf[6] + cf[7]*ky + cf[8]*kx + cf[9]*ky*ky + cf[10]*kx*ky + cf[11]*kx*kx;
          float Ipq = illum[(3*gi+p)*FW + 3*gj+q] * 0.125f;
          float ox[3], oy[3];
          #pragma unroll
          for (int d = 0; d < 3; d++){
            float xx = cx + (float)(d - 1);
            ox[d] = fmaxf(0.f, fminf(xx + sixth, 0.5f) - fmaxf(xx - sixth, -0.5f));
            float yy = cy + (float)(d - 1);
            oy[d] = fmaxf(0.f, fminf(yy + sixth, 0.5f) - fmaxf(yy - sixth, -0.5f));
          }
          #pragma unroll
          for (int d = 0; d < 3; d++){
            float aa = Ipq * ox[d];
            #pragma unroll
            for (int e = 0; e < 3; e++) Sv[d*3+e] = fmaf(aa, oy[e], Sv[d*3+e]);
          }
        }
      }
    }
    #pragma unroll
    for (int d = 0; d < 9; d++) S[d*324 + tid] = Sv[d];
  }
  __syncthreads();

  float chv = 0.f;
  if (tid < 256){
    int ti = tid >> 4, tj = tid & 15;
    float s = 0.f;
    #pragma unroll
    for (int d = 0; d < 3; d++)
      #pragma unroll
      for (int e = 0; e < 3; e++) s += S[(d*3+e)*324 + (ti+d)*18 + tj+e];
    int pix = ((gi0 + ti) << 8) + gj0 + tj;
    float nc = ws[WS_SENS + pix] * (9.f * s);
    float ch = ws[WS_CHARGE + pix] + nc;
    ws[WS_CHARGE + pix] = ch;
    out[(step + 1)*N2 + pix] = ch + ws[WS_MEDIAN];
    out[(9 + step)*N2 + pix] = ws[WS_ILLUM + pix] - nc;
    chv = ch;
  }
  block_sum_atomic(chv, ws + WS_SUMS + step + 1);
}

extern "C" void kernel_launch(void* const* d_in, const int* in_sizes, int n_in,
                              void* d_out, int out_size, void* d_ws, size_t ws_size,
                              hipStream_t stream) {
  (void)in_sizes; (void)n_in; (void)out_size; (void)ws_size;
  const float* bias  = (const float*)d_in[0];
  const float* illum = (const float*)d_in[1];
  const float* sens  = (const float*)d_in[2];
  const float* w1    = (const float*)d_in[3];
  const float* w2    = (const float*)d_in[4];
  const float* w3    = (const float*)d_in[5];
  float* out = (float*)d_out;
  float* ws  = (float*)d_ws;
  unsigned* H2 = (unsigned*)(ws + WS_H2);
  unsigned* H3 = (unsigned*)(ws + WS_H3);

  k_prep<<<8,   256, 0, stream>>>(w1, w2, w3, ws);
  k_h1  <<<64,  256, 0, stream>>>(bias, ws);
  k_s1  <<<1,  1024, 0, stream>>>(ws);
  k_h23 <<<64,  256, 0, stream>>>(bias, ws, H2, 10);
  k_s23 <<<1,  1024, 0, stream>>>(ws, H2, 0);
  k_h23 <<<64,  256, 0, stream>>>(bias, ws, H3, 0);
  k_s23 <<<1,  1024, 0, stream>>>(ws, H3, 1);
  k_init<<<256, 256, 0, stream>>>(bias, illum, sens, ws, out);
  for (int t = 0; t < 8; t++){
    k_convA<<<256, 512, 0, stream>>>(ws, ws + WS_W1T, ws + WS_W2T, t);
    k_convB<<<256, 512, 0, stream>>>(ws, ws + WS_W3T, illum, out, t);
  }
}

// Round 7
// 583.288 us; speedup vs baseline: 1.4262x; 1.1119x over previous
//
#include <hip/hip_runtime.h>

#define N2 65536
#define FW 768

// ---------------- workspace layout (float offsets) ----------------
#define WS_CHARGE 0
#define WS_ILLUM  (N2)
#define WS_SENS   (2*N2)
#define WS_FEAT2  (3*N2)              // 32 x 256 x 256, CHW
#define WS_W1T    (35*N2)             // [k*32+co]           288
#define WS_W2T    (WS_W1T + 288)      // [(ci*9+k)*32+co]    9216
#define WS_W3T    (WS_W2T + 9216)     // [(ci*9+k)*12+co]    3456
#define WS_SUMS   (WS_W3T + 3456)     // 9 charge sums
#define WS_BSUM   (WS_SUMS + 9)
#define WS_MEANB  (WS_SUMS + 10)
#define WS_MEDIAN (WS_SUMS + 11)
#define WS_SEL    (WS_SUMS + 12)      // 4 u32: selp0, selp1, selk0, selk1
#define WS_H2     (WS_SUMS + 16)      // 2048 u32
#define WS_H3     (WS_H2 + 2048)      // 2048 u32
#define NCLEAR    (16 + 2048 + 2048)
#define WS_H1     (WS_H3 + 2048)      // 32 slabs x 4096 u32 (fully overwritten)

__device__ __forceinline__ void block_sum_atomic(float v, float* dst){
  #pragma unroll
  for (int o = 32; o > 0; o >>= 1) v += __shfl_down(v, o, 64);
  __shared__ float red[16];
  int lane = threadIdx.x & 63, wid = threadIdx.x >> 6;
  int nw = (int)(blockDim.x >> 6);
  if (lane == 0) red[wid] = v;
  __syncthreads();
  if (threadIdx.x == 0){
    float s = red[0];
    for (int w = 1; w < nw; w++) s += red[w];
    atomicAdd(dst, s);
  }
}

// inclusive block scan (blockDim multiple of 64, <=1024)
__device__ __forceinline__ unsigned block_scan_u32(unsigned v, unsigned* wsum){
  __syncthreads();
  int lane = threadIdx.x & 63, wid = threadIdx.x >> 6, nw = (int)(blockDim.x >> 6);
  unsigned x = v;
  #pragma unroll
  for (int o = 1; o < 64; o <<= 1){ unsigned y = __shfl_up(x, o, 64); if (lane >= o) x += y; }
  if (lane == 63) wsum[wid] = x;
  __syncthreads();
  if (wid == 0){
    unsigned w = (lane < nw) ? wsum[lane] : 0u;
    #pragma unroll
    for (int o = 1; o < 16; o <<= 1){ unsigned y = __shfl_up(w, o, 64); if (lane >= o) w += y; }
    if (lane < nw) wsum[lane] = w;
  }
  __syncthreads();
  unsigned base = (wid > 0) ? wsum[wid - 1] : 0u;
  return base + x;
}

__device__ __forceinline__ unsigned key_flip(unsigned u){
  return (u & 0x80000000u) ? ~u : (u ^ 0x80000000u);
}

// ---- prep: zero small accumulator/hist region + weight transpose ----
__global__ __launch_bounds__(256) void k_prep(const float* __restrict__ w1,
    const float* __restrict__ w2, const float* __restrict__ w3,
    float* __restrict__ ws){
  int t = blockIdx.x * 256 + threadIdx.x;   // 2048 threads total
  unsigned* z = (unsigned*)(ws + WS_SUMS);
  for (int i = t; i < NCLEAR; i += 2048) z[i] = 0u;
  for (int idx = t; idx < 288; idx += 2048){
    int co = idx / 9, k = idx - co*9;
    ws[WS_W1T + k*32 + co] = w1[idx];
  }
  for (int idx = t; idx < 9216; idx += 2048){
    int co = idx / 288, r = idx - co*288, ci = r / 9, k = r - ci*9;
    ws[WS_W2T + (ci*9 + k)*32 + co] = w2[idx];
  }
  for (int idx = t; idx < 3456; idx += 2048){
    int co = idx / 288, r = idx - co*288, ci = r / 9, k = r - ci*9;
    ws[WS_W3T + (ci*9 + k)*12 + co] = w3[idx];
  }
}

// ---- level-1 histogram: per-block LDS hist -> atomic-free slab flush ----
__global__ __launch_bounds__(256) void k_h1(const float* __restrict__ bias,
                                            float* __restrict__ ws){
  __shared__ unsigned h[4096];
  for (int i = threadIdx.x; i < 4096; i += 256) h[i] = 0u;
  __syncthreads();
  float s = 0.f;
  for (int i = blockIdx.x * 256 + threadIdx.x; i < N2; i += 32*256){
    float v = bias[i]; s += v;
    atomicAdd(&h[key_flip(__float_as_uint(v)) >> 20], 1u);
  }
  __syncthreads();
  unsigned* H1 = (unsigned*)(ws + WS_H1) + (blockIdx.x << 12);
  for (int i = threadIdx.x; i < 4096; i += 256) H1[i] = h[i];
  block_sum_atomic(s, ws + WS_BSUM);
}

// ---- scan level-1: reduce 32 slabs, ranks 32767/32768 -> sel; mean ----
__global__ __launch_bounds__(1024) void k_s1(float* __restrict__ ws){
  const unsigned* H1 = (const unsigned*)(ws + WS_H1);
  unsigned* sel = (unsigned*)(ws + WS_SEL);
  __shared__ unsigned wssc[16];
  int t = threadIdx.x;
  uint4 hv = make_uint4(0u, 0u, 0u, 0u);
  for (int b = 0; b < 32; b++){
    uint4 v = ((const uint4*)(H1 + (b << 12)))[t];
    hv.x += v.x; hv.y += v.y; hv.z += v.z; hv.w += v.w;
  }
  unsigned c4 = hv.x + hv.y + hv.z + hv.w;
  unsigned cum = block_scan_u32(c4, wssc);
  unsigned before = cum - c4;
  unsigned hh[4] = {hv.x, hv.y, hv.z, hv.w};
  for (int s = 0; s < 2; s++){
    unsigned rank = 32767u + (unsigned)s;
    if (before <= rank && rank < cum){
      unsigned kk = rank - before, acc = 0; unsigned b = 0;
      for (; b < 3; b++){ if (acc + hh[b] > kk) break; acc += hh[b]; }
      sel[s]     = 4u*(unsigned)t + b;
      sel[2 + s] = kk - acc;
    }
  }
  if (t == 0) ws[WS_MEANB] = ws[WS_BSUM] * (1.f / (float)N2);
}

// ---- gated 1024-bin histogram (levels 2/3): ~32 matching elems only ----
__global__ __launch_bounds__(256) void k_h23(const float* __restrict__ bias,
    float* __restrict__ ws, unsigned* __restrict__ H, int shift){
  const unsigned* sel = (const unsigned*)(ws + WS_SEL);
  unsigned p0 = sel[0], p1 = sel[1];
  for (int i = blockIdx.x * 256 + threadIdx.x; i < N2; i += 64*256){
    unsigned key = key_flip(__float_as_uint(bias[i]));
    unsigned top = key >> (shift + 10);
    unsigned bin = (key >> shift) & 1023u;
    if (top == p0) atomicAdd(&H[bin], 1u);
    if (top == p1) atomicAdd(&H[1024u + bin], 1u);
  }
}

// ---- scan levels 2/3 ----
__global__ __launch_bounds__(1024) void k_s23(float* __restrict__ ws,
    const unsigned* __restrict__ H, int final_lvl){
  unsigned* sel = (unsigned*)(ws + WS_SEL);
  __shared__ unsigned wssc[16];
  __shared__ float meds[2];
  int t = threadIdx.x;
  for (int s = 0; s < 2; s++){
    unsigned cc = H[s*1024 + t];
    unsigned rank = sel[2 + s];
    unsigned cum = block_scan_u32(cc, wssc);
    unsigned before = cum - cc;
    if (before <= rank && rank < cum){
      unsigned p = (sel[s] << 10) | (unsigned)t;
      sel[s]     = p;
      sel[2 + s] = rank - before;
      if (final_lvl){
        unsigned u = (p & 0x80000000u) ? (p ^ 0x80000000u) : ~p;
        meds[s] = __uint_as_float(u);
      }
    }
    __syncthreads();
  }
  if (final_lvl && t == 0) ws[WS_MEDIAN] = 0.5f * (meds[0] + meds[1]);
}

// ---- init: downsample illum/sens, charge init, ramp[0], charge sum ----
__global__ __launch_bounds__(256) void k_init(const float* __restrict__ bias,
    const float* __restrict__ illum, const float* __restrict__ sens,
    float* __restrict__ ws, float* __restrict__ out){
  int pix = blockIdx.x * 256 + threadIdx.x;
  int i = pix >> 8, j = pix & 255;
  float si = 0.f, ss = 0.f;
  #pragma unroll
  for (int p = 0; p < 3; p++)
    #pragma unroll
    for (int q = 0; q < 3; q++){
      float se = sens[(3*i+p)*FW + 3*j+q];
      float il = illum[(3*i+p)*FW + 3*j+q];
      si = fmaf(se, il * 0.125f, si);
      ss += se;
    }
  ws[WS_ILLUM + pix] = si;
  ws[WS_SENS  + pix] = ss * (1.f/9.f);
  float c = bias[pix] - ws[WS_MEANB];
  ws[WS_CHARGE + pix] = c;
  out[pix] = c + ws[WS_MEDIAN];
  block_sum_atomic(c, ws + WS_SUMS + 0);
}

// ---- convA: conv1(1->32)+relu + conv2(32->32)+relu -> feat2 ----
// 512 blocks x 512 threads: block = (tile, co-half). 2 blocks/CU,
// 4 waves/SIMD. conv2: 8 waves x 2 co; lane = 4 px.
__global__ __launch_bounds__(512) void k_convA(float* __restrict__ ws,
    const float* __restrict__ w1t, const float* __restrict__ w2t, int step){
  __shared__ float chg[400];         // 20x20 charge tile (halo 2)
  __shared__ float f1[32*360];       // [ci][18 rows][20 cols]
  const float* charge = ws + WS_CHARGE;
  const float mean = ws[WS_SUMS + step] * (1.f / (float)N2);
  const int tile = blockIdx.x >> 1;
  const int half = blockIdx.x & 1;
  const int gi0 = (tile >> 4) << 4, gj0 = (tile & 15) << 4;
  const int tid = threadIdx.x;

  if (tid < 400){
    int r = tid / 20, c = tid - r*20;
    int gi = gi0 + r - 2, gj = gj0 + c - 2;
    float v = 0.f;
    if ((unsigned)gi < 256u && (unsigned)gj < 256u) v = charge[(gi<<8) + gj] - mean;
    chg[tid] = v;
  }
  __syncthreads();

  if (tid < 324){
    int r = tid / 18, c = tid - r*18;
    int gi = gi0 + r - 1, gj = gj0 + c - 1;
    float acc[32];
    #pragma unroll
    for (int co = 0; co < 32; co++) acc[co] = 0.f;
    if ((unsigned)gi < 256u && (unsigned)gj < 256u){
      float x[9];
      #pragma unroll
      for (int dy = 0; dy < 3; dy++)
        #pragma unroll
        for (int dx = 0; dx < 3; dx++) x[dy*3+dx] = chg[(r+dy)*20 + c+dx];
      #pragma unroll
      for (int k = 0; k < 9; k++){
        float xv = x[k];
        const float4* wr = (const float4*)(w1t + k*32);
        #pragma unroll
        for (int g = 0; g < 8; g++){
          float4 w4 = wr[g];
          acc[g*4+0] = fmaf(w4.x, xv, acc[g*4+0]);
          acc[g*4+1] = fmaf(w4.y, xv, acc[g*4+1]);
          acc[g*4+2] = fmaf(w4.z, xv, acc[g*4+2]);
          acc[g*4+3] = fmaf(w4.w, xv, acc[g*4+3]);
        }
      }
      #pragma unroll
      for (int co = 0; co < 32; co++) acc[co] = fmaxf(acc[co], 0.f);
    }
    #pragma unroll
    for (int co = 0; co < 32; co++) f1[co*360 + r*20 + c] = acc[co];
  }
  __syncthreads();

  const int lane = tid & 63;
  const int co2 = __builtin_amdgcn_readfirstlane(half*16 + ((tid >> 6) << 1));
  const int ti = lane >> 2, tjc = (lane & 3) << 2;
  float acc[4][2];
  #pragma unroll
  for (int p = 0; p < 4; p++){ acc[p][0] = 0.f; acc[p][1] = 0.f; }

  const float* wb = w2t + co2;
  for (int ci = 0; ci < 32; ci++){
    float xr[3][6];
    #pragma unroll
    for (int dy = 0; dy < 3; dy++){
      const float* rp = f1 + ci*360 + (ti+dy)*20 + tjc;
      float4 a = *(const float4*)rp;
      float2 b = *(const float2*)(rp + 4);
      xr[dy][0] = a.x; xr[dy][1] = a.y; xr[dy][2] = a.z; xr[dy][3] = a.w;
      xr[dy][4] = b.x; xr[dy][5] = b.y;
    }
    const float* wci = wb + ci*288;
    #pragma unroll
    for (int k = 0; k < 9; k++){
      const int dy = k / 3, dx = k - dy*3;
      float2 w2v = *(const float2*)(wci + k*32);
      #pragma unroll
      for (int p = 0; p < 4; p++){
        float xv = xr[dy][p + dx];
        acc[p][0] = fmaf(w2v.x, xv, acc[p][0]);
        acc[p][1] = fmaf(w2v.y, xv, acc[p][1]);
      }
    }
  }
  float* f2 = ws + WS_FEAT2;
  const int prow = ((gi0 + ti) << 8) + gj0 + tjc;
  #pragma unroll
  for (int cc = 0; cc < 2; cc++){
    float4 v;
    v.x = fmaxf(acc[0][cc], 0.f);
    v.y = fmaxf(acc[1][cc], 0.f);
    v.z = fmaxf(acc[2][cc], 0.f);
    v.w = fmaxf(acc[3][cc], 0.f);
    *(float4*)(f2 + (co2 + cc)*N2 + prow) = v;
  }
}

// ---- convB: conv3(32->12) on 18x18 halo (1 px/thread, registers only)
//      + distortion/overlap -> S (LDS) + fused apply. No atomics. ----
__global__ __launch_bounds__(512) void k_convB(float* __restrict__ ws,
    const float* __restrict__ w3t, const float* __restrict__ illum,
    float* __restrict__ out, int step){
  __shared__ float tile[32*400];     // [ci][20x20] f2 tile (halo 2)  51.2 KB
  __shared__ float S[9*324];         // S planes on 18x18             11.7 KB
  const float* f2 = ws + WS_FEAT2;
  const int gi0 = (blockIdx.x >> 4) << 4, gj0 = (blockIdx.x & 15) << 4;
  const int tid = threadIdx.x;

  for (int idx = tid; idx < 32*400; idx += 512){
    int ci = idx / 400, px = idx - ci*400, r = px / 20, c = px - r*20;
    int gi = gi0 + r - 2, gj = gj0 + c - 2;
    float v = 0.f;
    if ((unsigned)gi < 256u && (unsigned)gj < 256u) v = f2[ci*N2 + (gi<<8) + gj];
    tile[idx] = v;
  }
  __syncthreads();

  if (tid < 324){
    int a = tid / 18, b = tid - a*18;
    int gi = gi0 + a - 1, gj = gj0 + b - 1;
    float Sv[9];
    #pragma unroll
    for (int d = 0; d < 9; d++) Sv[d] = 0.f;
    if ((unsigned)gi < 256u && (unsigned)gj < 256u){
      float cf[12];
      #pragma unroll
      for (int co = 0; co < 12; co++) cf[co] = 0.f;
      for (int ci = 0; ci < 32; ci++){
        float x[9];
        #pragma unroll
        for (int dy = 0; dy < 3; dy++)
          #pragma unroll
          for (int dx = 0; dx < 3; dx++) x[dy*3+dx] = tile[ci*400 + (a+dy)*20 + (b+dx)];
        #pragma unroll
        for (int k = 0; k < 9; k++){
          const float4* wr = (const float4*)(w3t + (ci*9 + k)*12);
          float4 A = wr[0], B = wr[1], C = wr[2];
          float xv = x[k];
          cf[0] = fmaf(A.x, xv, cf[0]);   cf[1] = fmaf(A.y, xv, cf[1]);
          cf[2] = fmaf(A.z, xv, cf[2]);   cf[3] = fmaf(A.w, xv, cf[3]);
          cf[4] = fmaf(B.x, xv, cf[4]);   cf[5] = fmaf(B.y, xv, cf[5]);
          cf[6] = fmaf(B.z, xv, cf[6]);   cf[7] = fmaf(B.w, xv, cf[7]);
          cf[8] = fmaf(C.x, xv, cf[8]);   cf[9] = fmaf(C.y, xv, cf[9]);
          cf[10] = fmaf(C.z, xv, cf[10]); cf[11] = fmaf(C.w, xv, cf[11]);
        }
      }
      const float third = 1.f/3.f, sixth = 1.f/6.f;
      #pragma unroll
      for (int p = 0; p < 3; p++){
        float kx = (p - 1) * third;
        #pragma unroll
        for (int q = 0; q < 3; q++){
          float ky = (q - 1) * third;
          float cx = kx + cf[0] + cf[1]*ky + cf[2]*kx + cf[3]*ky*ky + cf[4]*kx*ky + cf[5]*kx*kx;
          float cy = ky + cf[6] + cf[7]*ky + cf[8]*kx + cf[9]*ky*ky + cf[10]*kx*ky + cf[11]*kx*kx;
          float Ipq = illum[(3*gi+p)*FW + 3*gj+q] * 0.125f;
          float ox[3], oy[3];
          #pragma unroll
          for (int d = 0; d < 3; d++){
            float xx = cx + (float)(d - 1);
            ox[d] = fmaxf(0.f, fminf(xx + sixth, 0.5f) - fmaxf(xx - sixth, -0.5f));
            float yy = cy + (float)(d - 1);
            oy[d] = fmaxf(0.f, fminf(yy + sixth, 0.5f) - fmaxf(yy - sixth, -0.5f));
          }
          #pragma unroll
          for (int d = 0; d < 3; d++){
            float aa = Ipq * ox[d];
            #pragma unroll
            for (int e = 0; e < 3; e++) Sv[d*3+e] = fmaf(aa, oy[e], Sv[d*3+e]);
          }
        }
      }
    }
    #pragma unroll
    for (int d = 0; d < 9; d++) S[d*324 + tid] = Sv[d];
  }
  __syncthreads();

  float chv = 0.f;
  if (tid < 256){
    int ti = tid >> 4, tj = tid & 15;
    float s = 0.f;
    #pragma unroll
    for (int d = 0; d < 3; d++)
      #pragma unroll
      for (int e = 0; e < 3; e++) s += S[(d*3+e)*324 + (ti+d)*18 + tj+e];
    int pix = ((gi0 + ti) << 8) + gj0 + tj;
    float nc = ws[WS_SENS + pix] * (9.f * s);
    float ch = ws[WS_CHARGE + pix] + nc;
    ws[WS_CHARGE + pix] = ch;
    out[(step + 1)*N2 + pix] = ch + ws[WS_MEDIAN];
    out[(9 + step)*N2 + pix] = ws[WS_ILLUM + pix] - nc;
    chv = ch;
  }
  block_sum_atomic(chv, ws + WS_SUMS + step + 1);
}

extern "C" void kernel_launch(void* const* d_in, const int* in_sizes, int n_in,
                              void* d_out, int out_size, void* d_ws, size_t ws_size,
                              hipStream_t stream) {
  (void)in_sizes; (void)n_in; (void)out_size; (void)ws_size;
  const float* bias  = (const float*)d_in[0];
  const float* illum = (const float*)d_in[1];
  const float* sens  = (const float*)d_in[2];
  const float* w1    = (const float*)d_in[3];
  const float* w2    = (const float*)d_in[4];
  const float* w3    = (const float*)d_in[5];
  float* out = (float*)d_out;
  float* ws  = (float*)d_ws;
  unsigned* H2 = (unsigned*)(ws + WS_H2);
  unsigned* H3 = (unsigned*)(ws + WS_H3);

  k_prep<<<8,   256, 0, stream>>>(w1, w2, w3, ws);
  k_h1  <<<32,  256, 0, stream>>>(bias, ws);
  k_s1  <<<1,  1024, 0, stream>>>(ws);
  k_h23 <<<64,  256, 0, stream>>>(bias, ws, H2, 10);
  k_s23 <<<1,  1024, 0, stream>>>(ws, H2, 0);
  k_h23 <<<64,  256, 0, stream>>>(bias, ws, H3, 0);
  k_s23 <<<1,  1024, 0, stream>>>(ws, H3, 1);
  k_init<<<256, 256, 0, stream>>>(bias, illum, sens, ws, out);
  for (int t = 0; t < 8; t++){
    k_convA<<<512, 512, 0, stream>>>(ws, ws + WS_W1T, ws + WS_W2T, t);
    k_convB<<<256, 512, 0, stream>>>(ws, ws + WS_W3T, illum, out, t);
  }
}